// Round 1
// baseline (428.144 us; speedup 1.0000x reference)
//
#include <hip/hip_runtime.h>
#include <hip/hip_bf16.h>
#include <float.h>

using bf16 = __hip_bfloat16;
typedef __attribute__((ext_vector_type(8))) short bf16x8;
typedef __attribute__((ext_vector_type(4))) float f32x4;

#define DIM   1024
#define NSEQ  4096
#define BATCH 2
#define NH    16
#define HD    64
#define NSEG  8
#define MSEG  512
#define ROWS  (BATCH*NSEQ)   // 8192
#define NC    (BATCH*NH)     // 32

// ---------------------------------------------------------------- rope table
__global__ void k_rope_tab(float* __restrict__ cosT, float* __restrict__ sinT) {
    int idx = blockIdx.x * 256 + threadIdx.x;     // 4096*32 = 131072
    int t = idx >> 5, i = idx & 31;
    float freq = 1.0f / powf(10000.0f, (float)(2 * i) * (1.0f / 64.0f));
    float a = (float)t * freq;
    cosT[idx] = cosf(a);
    sinT[idx] = sinf(a);
}

// ---------------------------------------------------------------- x -> bf16
__global__ void k_convert_x(const float* __restrict__ X, bf16* __restrict__ Xb) {
    int i = (blockIdx.x * 256 + threadIdx.x) * 4;
    float4 v = *(const float4*)&X[i];
    union { bf16 h[4]; uint2 u; } p;
    p.h[0] = __float2bfloat16(v.x);
    p.h[1] = __float2bfloat16(v.y);
    p.h[2] = __float2bfloat16(v.z);
    p.h[3] = __float2bfloat16(v.w);
    *(uint2*)&Xb[i] = p.u;
}

// ------------------------------------------- W[k][n] -> Wt[n][k] (bf16)
__global__ void k_transpose(const float* __restrict__ W, bf16* __restrict__ Wt) {
    __shared__ float tile[32][33];
    int bx = blockIdx.x * 32;   // n
    int by = blockIdx.y * 32;   // k
    int tx = threadIdx.x;
    for (int i = threadIdx.y; i < 32; i += 8)
        tile[i][tx] = W[(size_t)(by + i) * DIM + bx + tx];
    __syncthreads();
    for (int i = threadIdx.y; i < 32; i += 8)
        Wt[(size_t)(bx + i) * DIM + by + tx] = __float2bfloat16(tile[tx][i]);
}

// ---------------------------------------------------------------- GEMM core
// C[M=8192][N=1024] (fp32) = A(bf16, MxK row-major) * Bt(bf16, NxK row-major)^T
__launch_bounds__(256, 2)
__global__ void k_gemm_proj(const bf16* __restrict__ A, const bf16* __restrict__ Bt,
                            float* __restrict__ C) {
    __shared__ alignas(16) bf16 As[128][40];
    __shared__ alignas(16) bf16 Bs[128][40];
    const int K = DIM;
    int tid = threadIdx.x;
    int lane = tid & 63, wave = tid >> 6;
    int wr = (wave >> 1) * 64, wc = (wave & 1) * 64;
    int m0 = blockIdx.y * 128, n0 = blockIdx.x * 128;
    int lr = tid >> 2, lc = (tid & 3) * 8;
    int row = lane & 15, kk = (lane >> 4) * 8;
    f32x4 acc[4][4] = {};
    for (int k0 = 0; k0 < K; k0 += 32) {
        __syncthreads();
        *(bf16x8*)&As[lr][lc]      = *(const bf16x8*)&A[(size_t)(m0 + lr) * K + k0 + lc];
        *(bf16x8*)&As[lr + 64][lc] = *(const bf16x8*)&A[(size_t)(m0 + lr + 64) * K + k0 + lc];
        *(bf16x8*)&Bs[lr][lc]      = *(const bf16x8*)&Bt[(size_t)(n0 + lr) * K + k0 + lc];
        *(bf16x8*)&Bs[lr + 64][lc] = *(const bf16x8*)&Bt[(size_t)(n0 + lr + 64) * K + k0 + lc];
        __syncthreads();
        bf16x8 af[4], bfr[4];
#pragma unroll
        for (int mt = 0; mt < 4; ++mt) af[mt] = *(const bf16x8*)&As[wr + mt * 16 + row][kk];
#pragma unroll
        for (int nt = 0; nt < 4; ++nt) bfr[nt] = *(const bf16x8*)&Bs[wc + nt * 16 + row][kk];
#pragma unroll
        for (int mt = 0; mt < 4; ++mt)
#pragma unroll
            for (int nt = 0; nt < 4; ++nt)
                acc[mt][nt] = __builtin_amdgcn_mfma_f32_16x16x32_bf16(af[mt], bfr[nt], acc[mt][nt], 0, 0, 0);
    }
    int orow = (lane >> 4) * 4, ocol = lane & 15;
#pragma unroll
    for (int mt = 0; mt < 4; ++mt)
#pragma unroll
        for (int nt = 0; nt < 4; ++nt)
#pragma unroll
            for (int i = 0; i < 4; ++i)
                C[(size_t)(m0 + wr + mt * 16 + orow + i) * DIM + n0 + wc + nt * 16 + ocol] = acc[mt][nt][i];
}

// final GEMM: A = Ob (bf16), per-row-tile weight/bias select, fp32 out
__launch_bounds__(256, 2)
__global__ void k_gemm_out(const bf16* __restrict__ A, const bf16* __restrict__ Bt0,
                           const bf16* __restrict__ Bt1, const float* __restrict__ bias0,
                           const float* __restrict__ bias1, float* __restrict__ C) {
    __shared__ alignas(16) bf16 As[128][40];
    __shared__ alignas(16) bf16 Bs[128][40];
    const int K = DIM;
    int tid = threadIdx.x;
    int lane = tid & 63, wave = tid >> 6;
    int wr = (wave >> 1) * 64, wc = (wave & 1) * 64;
    int m0 = blockIdx.y * 128, n0 = blockIdx.x * 128;
    bool first = (m0 & (NSEQ - 1)) < MSEG;
    const bf16* Bt = first ? Bt0 : Bt1;
    const float* bias = first ? bias0 : bias1;
    int lr = tid >> 2, lc = (tid & 3) * 8;
    int row = lane & 15, kk = (lane >> 4) * 8;
    f32x4 acc[4][4] = {};
    for (int k0 = 0; k0 < K; k0 += 32) {
        __syncthreads();
        *(bf16x8*)&As[lr][lc]      = *(const bf16x8*)&A[(size_t)(m0 + lr) * K + k0 + lc];
        *(bf16x8*)&As[lr + 64][lc] = *(const bf16x8*)&A[(size_t)(m0 + lr + 64) * K + k0 + lc];
        *(bf16x8*)&Bs[lr][lc]      = *(const bf16x8*)&Bt[(size_t)(n0 + lr) * K + k0 + lc];
        *(bf16x8*)&Bs[lr + 64][lc] = *(const bf16x8*)&Bt[(size_t)(n0 + lr + 64) * K + k0 + lc];
        __syncthreads();
        bf16x8 af[4], bfr[4];
#pragma unroll
        for (int mt = 0; mt < 4; ++mt) af[mt] = *(const bf16x8*)&As[wr + mt * 16 + row][kk];
#pragma unroll
        for (int nt = 0; nt < 4; ++nt) bfr[nt] = *(const bf16x8*)&Bs[wc + nt * 16 + row][kk];
#pragma unroll
        for (int mt = 0; mt < 4; ++mt)
#pragma unroll
            for (int nt = 0; nt < 4; ++nt)
                acc[mt][nt] = __builtin_amdgcn_mfma_f32_16x16x32_bf16(af[mt], bfr[nt], acc[mt][nt], 0, 0, 0);
    }
    int orow = (lane >> 4) * 4, ocol = lane & 15;
#pragma unroll
    for (int mt = 0; mt < 4; ++mt)
#pragma unroll
        for (int nt = 0; nt < 4; ++nt) {
            float bv = bias[n0 + wc + nt * 16 + ocol];
#pragma unroll
            for (int i = 0; i < 4; ++i)
                C[(size_t)(m0 + wr + mt * 16 + orow + i) * DIM + n0 + wc + nt * 16 + ocol] = acc[mt][nt][i] + bv;
        }
}

// ---------------------------------------------------------------- RoPE (Q)
__global__ void k_rope_q(const float* __restrict__ Y, const float* __restrict__ cosT,
                         const float* __restrict__ sinT, bf16* __restrict__ Qb) {
    int idx = blockIdx.x * 256 + threadIdx.x;   // ROWS*DIM/2 threads
    int e = idx & 31;
    int head = (idx >> 5) & 15;
    int rowg = idx >> 9;                        // 0..8191
    int t = rowg & (NSEQ - 1), bidx = rowg >> 12;
    float x1 = Y[(size_t)rowg * DIM + head * HD + e];
    float x2 = Y[(size_t)rowg * DIM + head * HD + e + 32];
    float cv = cosT[t * 32 + e], sv = sinT[t * 32 + e];
    float o1 = (x1 * cv - x2 * sv) * 0.125f;    // * d^-0.5
    float o2 = (x2 * cv + x1 * sv) * 0.125f;
    int c = bidx * NH + head;
    size_t base = ((size_t)c * NSEQ + t) * HD;
    Qb[base + e]      = __float2bfloat16(o1);
    Qb[base + e + 32] = __float2bfloat16(o2);
}

// ---------------------------------------------------------------- RoPE (KV) + transpose
__global__ void k_rope_kv(const float* __restrict__ Y, const float* __restrict__ cosT,
                          const float* __restrict__ sinT, bf16* __restrict__ KVb,
                          bf16* __restrict__ KVt) {
    int idx = blockIdx.x * 256 + threadIdx.x;
    int e = idx & 31;
    int head = (idx >> 5) & 15;
    int rowg = idx >> 9;
    int t = rowg & (NSEQ - 1), bidx = rowg >> 12;
    float x1 = Y[(size_t)rowg * DIM + head * HD + e];
    float x2 = Y[(size_t)rowg * DIM + head * HD + e + 32];
    float cv = cosT[t * 32 + e], sv = sinT[t * 32 + e];
    float o1 = x1 * cv - x2 * sv;
    float o2 = x2 * cv + x1 * sv;
    int c = bidx * NH + head;
    size_t base = ((size_t)c * NSEQ + t) * HD;
    KVb[base + e]      = __float2bfloat16(o1);
    KVb[base + e + 32] = __float2bfloat16(o2);
    KVt[((size_t)c * HD + e) * NSEQ + t]      = __float2bfloat16(o1);
    KVt[((size_t)c * HD + e + 32) * NSEQ + t] = __float2bfloat16(o2);
}

// ---------------------------------------------------------------- attention
// grid: (rowgroup 0..7, seg 0..7, c 0..31); block 256 = 4 waves; wave = 16 q-rows
__launch_bounds__(256, 2)
__global__ void k_attn(const bf16* __restrict__ Qb, const bf16* __restrict__ KVb,
                       const bf16* __restrict__ KVt, bf16* __restrict__ Ob) {
    __shared__ alignas(16) bf16 P_lds[4][16][40];
    int lane = threadIdx.x & 63, wave = threadIdx.x >> 6;
    int c = blockIdx.z, seg = blockIdx.y;
    int i0 = blockIdx.x * 64 + wave * 16;       // q-row offset within segment
    int bidx = c >> 4, head = c & 15;
    int row = lane & 15, kk = (lane >> 4) * 8;
    int tq = seg * MSEG + i0 + row;
    const bf16* qptr = &Qb[((size_t)c * NSEQ + tq) * HD];
    bf16x8 qf0 = *(const bf16x8*)&qptr[kk];
    bf16x8 qf1 = *(const bf16x8*)&qptr[32 + kk];
    f32x4 o[4] = {};
    float mx[4], ls[4];
#pragma unroll
    for (int i = 0; i < 4; ++i) { mx[i] = -FLT_MAX; ls[i] = 0.f; }
    int kvbase = (seg == 0) ? 0 : (seg - 1) * MSEG;
    int width  = (seg == 0) ? MSEG : 2 * MSEG;
    int cstart = (seg == 0) ? 0 : MSEG;         // cols >= cstart are causal vs local row
    int rl0 = i0 + (lane >> 4) * 4;
    for (int c0 = 0; c0 < width; c0 += 32) {
        if (c0 >= cstart + i0 + 16) break;      // fully masked beyond
        f32x4 s[2];
#pragma unroll
        for (int sub = 0; sub < 2; ++sub) {
            int col = c0 + sub * 16 + row;
            const bf16* kp = &KVb[((size_t)c * NSEQ + kvbase + col) * HD];
            bf16x8 kf0 = *(const bf16x8*)&kp[kk];
            bf16x8 kf1 = *(const bf16x8*)&kp[32 + kk];
            f32x4 a = {};
            a = __builtin_amdgcn_mfma_f32_16x16x32_bf16(qf0, kf0, a, 0, 0, 0);
            a = __builtin_amdgcn_mfma_f32_16x16x32_bf16(qf1, kf1, a, 0, 0, 0);
            s[sub] = a;
        }
        int colb0 = c0 + (lane & 15);
        int colb1 = c0 + 16 + (lane & 15);
#pragma unroll
        for (int i = 0; i < 4; ++i) {
            int rl = rl0 + i;
            if (colb0 >= cstart && (colb0 - cstart) > rl) s[0][i] = -FLT_MAX;
            if (colb1 >= cstart && (colb1 - cstart) > rl) s[1][i] = -FLT_MAX;
        }
        float p0[4], p1[4];
#pragma unroll
        for (int i = 0; i < 4; ++i) {
            float v = fmaxf(s[0][i], s[1][i]);
            v = fmaxf(v, __shfl_xor(v, 1));
            v = fmaxf(v, __shfl_xor(v, 2));
            v = fmaxf(v, __shfl_xor(v, 4));
            v = fmaxf(v, __shfl_xor(v, 8));
            float nm = fmaxf(mx[i], v);
            float al = __expf(mx[i] - nm);
            p0[i] = __expf(s[0][i] - nm);
            p1[i] = __expf(s[1][i] - nm);
            float sm = p0[i] + p1[i];
            sm += __shfl_xor(sm, 1);
            sm += __shfl_xor(sm, 2);
            sm += __shfl_xor(sm, 4);
            sm += __shfl_xor(sm, 8);
            ls[i] = ls[i] * al + sm;
            mx[i] = nm;
#pragma unroll
            for (int nt = 0; nt < 4; ++nt) o[nt][i] *= al;
        }
        // P (D-layout) -> LDS -> A-fragment layout
#pragma unroll
        for (int i = 0; i < 4; ++i) {
            int r = (lane >> 4) * 4 + i;
            P_lds[wave][r][lane & 15]      = __float2bfloat16(p0[i]);
            P_lds[wave][r][16 + (lane & 15)] = __float2bfloat16(p1[i]);
        }
        asm volatile("s_waitcnt lgkmcnt(0)" ::: "memory");
        __builtin_amdgcn_sched_barrier(0);
        bf16x8 pa = *(const bf16x8*)&P_lds[wave][lane & 15][kk];
#pragma unroll
        for (int nt = 0; nt < 4; ++nt) {
            const bf16* vp = &KVt[((size_t)c * HD + nt * 16 + (lane & 15)) * NSEQ + kvbase + c0 + kk];
            bf16x8 vf = *(const bf16x8*)vp;
            o[nt] = __builtin_amdgcn_mfma_f32_16x16x32_bf16(pa, vf, o[nt], 0, 0, 0);
        }
        asm volatile("s_waitcnt lgkmcnt(0)" ::: "memory");
        __builtin_amdgcn_sched_barrier(0);
    }
#pragma unroll
    for (int i = 0; i < 4; ++i) {
        float inv = 1.0f / ls[i];
        int t = seg * MSEG + rl0 + i;
        size_t base = ((size_t)bidx * NSEQ + t) * DIM + head * HD;
#pragma unroll
        for (int nt = 0; nt < 4; ++nt)
            Ob[base + nt * 16 + (lane & 15)] = __float2bfloat16(o[nt][i] * inv);
    }
}

// ---------------------------------------------------------------- launch
extern "C" void kernel_launch(void* const* d_in, const int* in_sizes, int n_in,
                              void* d_out, int out_size, void* d_ws, size_t ws_size,
                              hipStream_t stream) {
    const float* x   = (const float*)d_in[0];
    const float* Wq  = (const float*)d_in[1];
    const float* Wkv = (const float*)d_in[2];
    const float* Wo  = (const float*)d_in[3];
    const float* bo  = (const float*)d_in[4];
    const float* Wo0 = (const float*)d_in[5];
    const float* bo0 = (const float*)d_in[6];
    float* out = (float*)d_out;

    char* ws = (char*)d_ws;
    size_t off = 0;
    auto alloc = [&](size_t bytes) { void* p = ws + off; off += (bytes + 255) & ~(size_t)255; return p; };
    float* cosT = (float*)alloc((size_t)NSEQ * 32 * 4);
    float* sinT = (float*)alloc((size_t)NSEQ * 32 * 4);
    bf16* Xb    = (bf16*)alloc((size_t)ROWS * DIM * 2);
    bf16* WqT   = (bf16*)alloc((size_t)DIM * DIM * 2);
    bf16* WkvT  = (bf16*)alloc((size_t)DIM * DIM * 2);
    bf16* WoT   = (bf16*)alloc((size_t)DIM * DIM * 2);
    bf16* Wo0T  = (bf16*)alloc((size_t)DIM * DIM * 2);
    float* Y    = (float*)alloc((size_t)ROWS * DIM * 4);
    bf16* Qb    = (bf16*)alloc((size_t)NC * NSEQ * HD * 2);
    bf16* KVb   = (bf16*)alloc((size_t)NC * NSEQ * HD * 2);
    bf16* KVt   = (bf16*)alloc((size_t)NC * HD * NSEQ * 2);
    bf16* Ob    = (bf16*)alloc((size_t)ROWS * DIM * 2);

    hipLaunchKernelGGL(k_rope_tab, dim3(NSEQ * 32 / 256), dim3(256), 0, stream, cosT, sinT);
    hipLaunchKernelGGL(k_convert_x, dim3(ROWS * DIM / 4 / 256), dim3(256), 0, stream, x, Xb);
    hipLaunchKernelGGL(k_transpose, dim3(32, 32), dim3(32, 8), 0, stream, Wq, WqT);
    hipLaunchKernelGGL(k_transpose, dim3(32, 32), dim3(32, 8), 0, stream, Wkv, WkvT);
    hipLaunchKernelGGL(k_transpose, dim3(32, 32), dim3(32, 8), 0, stream, Wo, WoT);
    hipLaunchKernelGGL(k_transpose, dim3(32, 32), dim3(32, 8), 0, stream, Wo0, Wo0T);

    hipLaunchKernelGGL(k_gemm_proj, dim3(8, 64), dim3(256), 0, stream, Xb, WqT, Y);
    hipLaunchKernelGGL(k_rope_q, dim3(ROWS * DIM / 2 / 256), dim3(256), 0, stream, Y, cosT, sinT, Qb);
    hipLaunchKernelGGL(k_gemm_proj, dim3(8, 64), dim3(256), 0, stream, Xb, WkvT, Y);
    hipLaunchKernelGGL(k_rope_kv, dim3(ROWS * DIM / 2 / 256), dim3(256), 0, stream, Y, cosT, sinT, KVb, KVt);

    hipLaunchKernelGGL(k_attn, dim3(8, 8, 32), dim3(256), 0, stream, Qb, KVb, KVt, Ob);

    hipLaunchKernelGGL(k_gemm_out, dim3(8, 64), dim3(256), 0, stream, Ob, Wo0T, WoT, bo0, bo, out);
}

// Round 2
// 285.632 us; speedup vs baseline: 1.4989x; 1.4989x over previous
//
#include <hip/hip_runtime.h>
#include <hip/hip_bf16.h>
#include <float.h>

using bf16 = __hip_bfloat16;
typedef __attribute__((ext_vector_type(8))) short bf16x8;
typedef __attribute__((ext_vector_type(4))) float f32x4;
typedef __attribute__((ext_vector_type(16))) float f32x16;

#define DIM   1024
#define NSEQ  4096
#define BATCH 2
#define NH    16
#define HD    64
#define NSEG  8
#define MSEG  512
#define ROWS  (BATCH*NSEQ)   // 8192
#define NC    (BATCH*NH)     // 32

__device__ __forceinline__ void gload16(const bf16* g, bf16* l) {
    __builtin_amdgcn_global_load_lds((const __attribute__((address_space(1))) unsigned int*)g,
                                     (__attribute__((address_space(3))) unsigned int*)l, 16, 0, 0);
}

// ---------------------------------------------------------------- rope table
__global__ void k_rope_tab(float* __restrict__ cosT, float* __restrict__ sinT) {
    int idx = blockIdx.x * 256 + threadIdx.x;     // 4096*32 = 131072
    int t = idx >> 5, i = idx & 31;
    float freq = 1.0f / powf(10000.0f, (float)(2 * i) * (1.0f / 64.0f));
    float a = (float)t * freq;
    cosT[idx] = cosf(a);
    sinT[idx] = sinf(a);
}

// ---------------------------------------------------------------- x -> bf16
__global__ void k_convert_x(const float* __restrict__ X, bf16* __restrict__ Xb) {
    int i = (blockIdx.x * 256 + threadIdx.x) * 4;
    float4 v = *(const float4*)&X[i];
    union { bf16 h[4]; uint2 u; } p;
    p.h[0] = __float2bfloat16(v.x);
    p.h[1] = __float2bfloat16(v.y);
    p.h[2] = __float2bfloat16(v.z);
    p.h[3] = __float2bfloat16(v.w);
    *(uint2*)&Xb[i] = p.u;
}

// ------------------------------------------- W[k][n] -> Wt[n][k] (bf16)
__global__ void k_transpose(const float* __restrict__ W, bf16* __restrict__ Wt) {
    __shared__ float tile[32][33];
    int bx = blockIdx.x * 32;   // n
    int by = blockIdx.y * 32;   // k
    int tx = threadIdx.x;
    for (int i = threadIdx.y; i < 32; i += 8)
        tile[i][tx] = W[(size_t)(by + i) * DIM + bx + tx];
    __syncthreads();
    for (int i = threadIdx.y; i < 32; i += 8)
        Wt[(size_t)(bx + i) * DIM + by + tx] = __float2bfloat16(tile[tx][i]);
}

// ---------------------------------------------------------------- GEMM core (m97 structure)
// C[8192][1024] (fp32) = A(bf16 MxK rm) * Bt(bf16 NxK rm)^T ; BK=32, global_load_lds staging
__launch_bounds__(256, 2)
__global__ void k_gemm_proj(const bf16* __restrict__ A, const bf16* __restrict__ Bt,
                            float* __restrict__ C) {
    __shared__ alignas(16) bf16 As[128 * 32];
    __shared__ alignas(16) bf16 Bs[128 * 32];
    const int K = DIM;
    int tid = threadIdx.x;
    int lane = tid & 63, wave = tid >> 6;
    int wr = (wave >> 1) * 64, wc = (wave & 1) * 64;
    int m0 = blockIdx.y * 128, n0 = blockIdx.x * 128;
    int row = lane & 15, kk = (lane >> 4) * 8;
    // staging: chunk = wave*128 + l*64 + lane ; row=chunk>>2, col=(chunk&3)*8
    int ch0 = wave * 128 + lane;
    int ch1 = ch0 + 64;
    int r0 = ch0 >> 2, c0e = (ch0 & 3) * 8;
    int r1 = ch1 >> 2, c1e = (ch1 & 3) * 8;
    bf16* ldsA0 = &As[wave * 1024];
    bf16* ldsA1 = &As[wave * 1024 + 512];
    bf16* ldsB0 = &Bs[wave * 1024];
    bf16* ldsB1 = &Bs[wave * 1024 + 512];
    f32x4 acc[4][4] = {};
    for (int k0 = 0; k0 < K; k0 += 32) {
        __syncthreads();
        gload16(&A[(size_t)(m0 + r0) * K + k0 + c0e], ldsA0);
        gload16(&A[(size_t)(m0 + r1) * K + k0 + c1e], ldsA1);
        gload16(&Bt[(size_t)(n0 + r0) * K + k0 + c0e], ldsB0);
        gload16(&Bt[(size_t)(n0 + r1) * K + k0 + c1e], ldsB1);
        __syncthreads();
        bf16x8 af[4], bfr[4];
#pragma unroll
        for (int mt = 0; mt < 4; ++mt) af[mt] = *(const bf16x8*)&As[(wr + mt * 16 + row) * 32 + kk];
#pragma unroll
        for (int nt = 0; nt < 4; ++nt) bfr[nt] = *(const bf16x8*)&Bs[(wc + nt * 16 + row) * 32 + kk];
#pragma unroll
        for (int mt = 0; mt < 4; ++mt)
#pragma unroll
            for (int nt = 0; nt < 4; ++nt)
                acc[mt][nt] = __builtin_amdgcn_mfma_f32_16x16x32_bf16(af[mt], bfr[nt], acc[mt][nt], 0, 0, 0);
    }
    int orow = (lane >> 4) * 4, ocol = lane & 15;
#pragma unroll
    for (int mt = 0; mt < 4; ++mt)
#pragma unroll
        for (int nt = 0; nt < 4; ++nt)
#pragma unroll
            for (int i = 0; i < 4; ++i)
                C[(size_t)(m0 + wr + mt * 16 + orow + i) * DIM + n0 + wc + nt * 16 + ocol] = acc[mt][nt][i];
}

// final GEMM: per-row-tile weight/bias select, fp32 out
__launch_bounds__(256, 2)
__global__ void k_gemm_out(const bf16* __restrict__ A, const bf16* __restrict__ Bt0,
                           const bf16* __restrict__ Bt1, const float* __restrict__ bias0,
                           const float* __restrict__ bias1, float* __restrict__ C) {
    __shared__ alignas(16) bf16 As[128 * 32];
    __shared__ alignas(16) bf16 Bs[128 * 32];
    const int K = DIM;
    int tid = threadIdx.x;
    int lane = tid & 63, wave = tid >> 6;
    int wr = (wave >> 1) * 64, wc = (wave & 1) * 64;
    int m0 = blockIdx.y * 128, n0 = blockIdx.x * 128;
    bool first = (m0 & (NSEQ - 1)) < MSEG;
    const bf16* Bt = first ? Bt0 : Bt1;
    const float* bias = first ? bias0 : bias1;
    int row = lane & 15, kk = (lane >> 4) * 8;
    int ch0 = wave * 128 + lane;
    int ch1 = ch0 + 64;
    int r0 = ch0 >> 2, c0e = (ch0 & 3) * 8;
    int r1 = ch1 >> 2, c1e = (ch1 & 3) * 8;
    bf16* ldsA0 = &As[wave * 1024];
    bf16* ldsA1 = &As[wave * 1024 + 512];
    bf16* ldsB0 = &Bs[wave * 1024];
    bf16* ldsB1 = &Bs[wave * 1024 + 512];
    f32x4 acc[4][4] = {};
    for (int k0 = 0; k0 < K; k0 += 32) {
        __syncthreads();
        gload16(&A[(size_t)(m0 + r0) * K + k0 + c0e], ldsA0);
        gload16(&A[(size_t)(m0 + r1) * K + k0 + c1e], ldsA1);
        gload16(&Bt[(size_t)(n0 + r0) * K + k0 + c0e], ldsB0);
        gload16(&Bt[(size_t)(n0 + r1) * K + k0 + c1e], ldsB1);
        __syncthreads();
        bf16x8 af[4], bfr[4];
#pragma unroll
        for (int mt = 0; mt < 4; ++mt) af[mt] = *(const bf16x8*)&As[(wr + mt * 16 + row) * 32 + kk];
#pragma unroll
        for (int nt = 0; nt < 4; ++nt) bfr[nt] = *(const bf16x8*)&Bs[(wc + nt * 16 + row) * 32 + kk];
#pragma unroll
        for (int mt = 0; mt < 4; ++mt)
#pragma unroll
            for (int nt = 0; nt < 4; ++nt)
                acc[mt][nt] = __builtin_amdgcn_mfma_f32_16x16x32_bf16(af[mt], bfr[nt], acc[mt][nt], 0, 0, 0);
    }
    int orow = (lane >> 4) * 4, ocol = lane & 15;
#pragma unroll
    for (int mt = 0; mt < 4; ++mt)
#pragma unroll
        for (int nt = 0; nt < 4; ++nt) {
            float bv = bias[n0 + wc + nt * 16 + ocol];
#pragma unroll
            for (int i = 0; i < 4; ++i)
                C[(size_t)(m0 + wr + mt * 16 + orow + i) * DIM + n0 + wc + nt * 16 + ocol] = acc[mt][nt][i] + bv;
        }
}

// ---------------------------------------------------------------- RoPE (Q)
__global__ void k_rope_q(const float* __restrict__ Y, const float* __restrict__ cosT,
                         const float* __restrict__ sinT, bf16* __restrict__ Qb) {
    int idx = blockIdx.x * 256 + threadIdx.x;   // ROWS*DIM/2 threads
    int e = idx & 31;
    int head = (idx >> 5) & 15;
    int rowg = idx >> 9;                        // 0..8191
    int t = rowg & (NSEQ - 1), bidx = rowg >> 12;
    float x1 = Y[(size_t)rowg * DIM + head * HD + e];
    float x2 = Y[(size_t)rowg * DIM + head * HD + e + 32];
    float cv = cosT[t * 32 + e], sv = sinT[t * 32 + e];
    float o1 = (x1 * cv - x2 * sv) * 0.125f;    // * d^-0.5
    float o2 = (x2 * cv + x1 * sv) * 0.125f;
    int c = bidx * NH + head;
    size_t base = ((size_t)c * NSEQ + t) * HD;
    Qb[base + e]      = __float2bfloat16(o1);
    Qb[base + e + 32] = __float2bfloat16(o2);
}

// ---------------------------------------------------------------- RoPE (KV) + transpose
__global__ void k_rope_kv(const float* __restrict__ Y, const float* __restrict__ cosT,
                          const float* __restrict__ sinT, bf16* __restrict__ KVb,
                          bf16* __restrict__ KVt) {
    int idx = blockIdx.x * 256 + threadIdx.x;
    int e = idx & 31;
    int head = (idx >> 5) & 15;
    int rowg = idx >> 9;
    int t = rowg & (NSEQ - 1), bidx = rowg >> 12;
    float x1 = Y[(size_t)rowg * DIM + head * HD + e];
    float x2 = Y[(size_t)rowg * DIM + head * HD + e + 32];
    float cv = cosT[t * 32 + e], sv = sinT[t * 32 + e];
    float o1 = x1 * cv - x2 * sv;
    float o2 = x2 * cv + x1 * sv;
    int c = bidx * NH + head;
    size_t base = ((size_t)c * NSEQ + t) * HD;
    KVb[base + e]      = __float2bfloat16(o1);
    KVb[base + e + 32] = __float2bfloat16(o2);
    KVt[((size_t)c * HD + e) * NSEQ + t]      = __float2bfloat16(o1);
    KVt[((size_t)c * HD + e + 32) * NSEQ + t] = __float2bfloat16(o2);
}

// ---------------------------------------------------------------- attention (swapped-QK 32x32)
// grid: (rowgroup 0..3, seg 0..7, c 0..31); block 256 = 4 waves; wave = 32 q-rows; no LDS
__launch_bounds__(256, 2)
__global__ void k_attn(const bf16* __restrict__ Qb, const bf16* __restrict__ KVb,
                       const bf16* __restrict__ KVt, bf16* __restrict__ Ob) {
    int lane = threadIdx.x & 63, wave = threadIdx.x >> 6;
    int hi = lane >> 5, lq = lane & 31;
    int c = blockIdx.z, seg = blockIdx.y;
    int i0 = blockIdx.x * 128 + wave * 32;      // q-row offset within segment
    int bidx = c >> 4, head = c & 15;
    int tq = seg * MSEG + i0 + lq;
    const bf16* qptr = &Qb[((size_t)c * NSEQ + tq) * HD + hi * 8];
    bf16x8 qf[4];
#pragma unroll
    for (int dc = 0; dc < 4; ++dc) qf[dc] = *(const bf16x8*)&qptr[dc * 16];
    f32x16 o0 = {}, o1 = {};
    float mrun = -FLT_MAX, lrun = 0.f;
    int kvbase = (seg == 0) ? 0 : (seg - 1) * MSEG;
    int cstart = (seg == 0) ? 0 : MSEG;         // cols >= cstart are causal vs local row
    int cend = cstart + i0 + 32;
    for (int c0 = 0; c0 < cend; c0 += 32) {
        // K fragments: A[row=kv=lq][k=d], 4 d-chunks of 16
        const bf16* kp = &KVb[((size_t)c * NSEQ + kvbase + c0 + lq) * HD + hi * 8];
        bf16x8 kf0 = *(const bf16x8*)&kp[0];
        bf16x8 kf1 = *(const bf16x8*)&kp[16];
        bf16x8 kf2 = *(const bf16x8*)&kp[32];
        bf16x8 kf3 = *(const bf16x8*)&kp[48];
        // V^T fragments: A[row=d=dt*32+lq][k=kv], 2 d-tiles x 2 kv-chunks of 16
        const bf16* vpb = &KVt[((size_t)c * HD + lq) * NSEQ + kvbase + c0 + hi * 8];
        bf16x8 vf00 = *(const bf16x8*)&vpb[0];
        bf16x8 vf01 = *(const bf16x8*)&vpb[16];
        bf16x8 vf10 = *(const bf16x8*)&vpb[(size_t)32 * NSEQ];
        bf16x8 vf11 = *(const bf16x8*)&vpb[(size_t)32 * NSEQ + 16];
        // S^T[kv][q] : lane holds q=lq, kv = (r&3)+8*(r>>2)+4*hi
        f32x16 s = {};
        s = __builtin_amdgcn_mfma_f32_32x32x16_bf16(kf0, qf[0], s, 0, 0, 0);
        s = __builtin_amdgcn_mfma_f32_32x32x16_bf16(kf1, qf[1], s, 0, 0, 0);
        s = __builtin_amdgcn_mfma_f32_32x32x16_bf16(kf2, qf[2], s, 0, 0, 0);
        s = __builtin_amdgcn_mfma_f32_32x32x16_bf16(kf3, qf[3], s, 0, 0, 0);
        if (c0 + 31 >= cstart && c0 + 31 - cstart > i0) {
#pragma unroll
            for (int r = 0; r < 16; ++r) {
                int kvg = c0 + ((r & 3) + 8 * (r >> 2) + 4 * hi);
                if (kvg >= cstart && kvg - cstart > i0 + lq) s[r] = -FLT_MAX;
            }
        }
        // online softmax: per lane owns one q-row (half the kv in lane^32)
        float vmax = fmaxf(s[0], s[1]);
#pragma unroll
        for (int r = 2; r < 16; ++r) vmax = fmaxf(vmax, s[r]);
        vmax = fmaxf(vmax, __shfl_xor(vmax, 32));
        float nm = fmaxf(mrun, vmax);
        float al = __expf(mrun - nm);
        float p[16], sum = 0.f;
#pragma unroll
        for (int r = 0; r < 16; ++r) { p[r] = __expf(s[r] - nm); sum += p[r]; }
        sum += __shfl_xor(sum, 32);
        lrun = lrun * al + sum;
        mrun = nm;
#pragma unroll
        for (int r = 0; r < 16; ++r) { o0[r] *= al; o1[r] *= al; }
        // P^T -> B-fragment: pack pairs to bf16, exchange halves via shfl_xor(32)
        unsigned pk[8], sw[8];
#pragma unroll
        for (int k = 0; k < 8; ++k) {
            union { bf16 h[2]; unsigned u; } cv;
            cv.h[0] = __float2bfloat16(p[2 * k]);
            cv.h[1] = __float2bfloat16(p[2 * k + 1]);
            pk[k] = cv.u;
        }
#pragma unroll
        for (int k = 0; k < 8; ++k) sw[k] = (unsigned)__shfl_xor((int)pk[k], 32);
        union { unsigned u[4]; bf16x8 v; } b0, b1;
        if (hi == 0) {
            b0.u[0] = pk[0]; b0.u[1] = pk[1]; b0.u[2] = sw[0]; b0.u[3] = sw[1];
            b1.u[0] = pk[4]; b1.u[1] = pk[5]; b1.u[2] = sw[4]; b1.u[3] = sw[5];
        } else {
            b0.u[0] = sw[2]; b0.u[1] = sw[3]; b0.u[2] = pk[2]; b0.u[3] = pk[3];
            b1.u[0] = sw[6]; b1.u[1] = sw[7]; b1.u[2] = pk[6]; b1.u[3] = pk[7];
        }
        // O^T[d][q] += V^T P^T
        o0 = __builtin_amdgcn_mfma_f32_32x32x16_bf16(vf00, b0.v, o0, 0, 0, 0);
        o0 = __builtin_amdgcn_mfma_f32_32x32x16_bf16(vf01, b1.v, o0, 0, 0, 0);
        o1 = __builtin_amdgcn_mfma_f32_32x32x16_bf16(vf10, b0.v, o1, 0, 0, 0);
        o1 = __builtin_amdgcn_mfma_f32_32x32x16_bf16(vf11, b1.v, o1, 0, 0, 0);
    }
    float inv = 1.0f / lrun;
    size_t obase = ((size_t)bidx * NSEQ + tq) * DIM + head * HD;
#pragma unroll
    for (int dt = 0; dt < 2; ++dt)
#pragma unroll
        for (int a = 0; a < 4; ++a) {
            union { bf16 h[4]; uint2 u; } pkd;
            const f32x16& ov = dt ? o1 : o0;
#pragma unroll
            for (int i = 0; i < 4; ++i) pkd.h[i] = __float2bfloat16(ov[4 * a + i] * inv);
            *(uint2*)&Ob[obase + dt * 32 + 8 * a + 4 * hi] = pkd.u;
        }
}

// ---------------------------------------------------------------- launch
extern "C" void kernel_launch(void* const* d_in, const int* in_sizes, int n_in,
                              void* d_out, int out_size, void* d_ws, size_t ws_size,
                              hipStream_t stream) {
    const float* x   = (const float*)d_in[0];
    const float* Wq  = (const float*)d_in[1];
    const float* Wkv = (const float*)d_in[2];
    const float* Wo  = (const float*)d_in[3];
    const float* bo  = (const float*)d_in[4];
    const float* Wo0 = (const float*)d_in[5];
    const float* bo0 = (const float*)d_in[6];
    float* out = (float*)d_out;

    char* ws = (char*)d_ws;
    size_t off = 0;
    auto alloc = [&](size_t bytes) { void* p = ws + off; off += (bytes + 255) & ~(size_t)255; return p; };
    float* cosT = (float*)alloc((size_t)NSEQ * 32 * 4);
    float* sinT = (float*)alloc((size_t)NSEQ * 32 * 4);
    bf16* Xb    = (bf16*)alloc((size_t)ROWS * DIM * 2);
    bf16* WqT   = (bf16*)alloc((size_t)DIM * DIM * 2);
    bf16* WkvT  = (bf16*)alloc((size_t)DIM * DIM * 2);
    bf16* WoT   = (bf16*)alloc((size_t)DIM * DIM * 2);
    bf16* Wo0T  = (bf16*)alloc((size_t)DIM * DIM * 2);
    float* Y    = (float*)alloc((size_t)ROWS * DIM * 4);
    bf16* Qb    = (bf16*)alloc((size_t)NC * NSEQ * HD * 2);
    bf16* KVb   = (bf16*)alloc((size_t)NC * NSEQ * HD * 2);
    bf16* KVt   = (bf16*)alloc((size_t)NC * HD * NSEQ * 2);
    bf16* Ob    = (bf16*)alloc((size_t)ROWS * DIM * 2);

    hipLaunchKernelGGL(k_rope_tab, dim3(NSEQ * 32 / 256), dim3(256), 0, stream, cosT, sinT);
    hipLaunchKernelGGL(k_convert_x, dim3(ROWS * DIM / 4 / 256), dim3(256), 0, stream, x, Xb);
    hipLaunchKernelGGL(k_transpose, dim3(32, 32), dim3(32, 8), 0, stream, Wq, WqT);
    hipLaunchKernelGGL(k_transpose, dim3(32, 32), dim3(32, 8), 0, stream, Wkv, WkvT);
    hipLaunchKernelGGL(k_transpose, dim3(32, 32), dim3(32, 8), 0, stream, Wo, WoT);
    hipLaunchKernelGGL(k_transpose, dim3(32, 32), dim3(32, 8), 0, stream, Wo0, Wo0T);

    hipLaunchKernelGGL(k_gemm_proj, dim3(8, 64), dim3(256), 0, stream, Xb, WqT, Y);
    hipLaunchKernelGGL(k_rope_q, dim3(ROWS * DIM / 2 / 256), dim3(256), 0, stream, Y, cosT, sinT, Qb);
    hipLaunchKernelGGL(k_gemm_proj, dim3(8, 64), dim3(256), 0, stream, Xb, WkvT, Y);
    hipLaunchKernelGGL(k_rope_kv, dim3(ROWS * DIM / 2 / 256), dim3(256), 0, stream, Y, cosT, sinT, KVb, KVt);

    hipLaunchKernelGGL(k_attn, dim3(4, 8, 32), dim3(256), 0, stream, Qb, KVb, KVt, Ob);

    hipLaunchKernelGGL(k_gemm_out, dim3(8, 64), dim3(256), 0, stream, Ob, Wo0T, WoT, bo0, bo, out);
}